// Round 9
// baseline (200.739 us; speedup 1.0000x reference)
//
#include <hip/hip_runtime.h>
#include <math.h>
#include <stdint.h>

// VectorQuantizer on MI355X (gfx950). N=131072, D=64, K=2048, fp32.
// Round 9: r8 two-pass + (1) RG=4/WPB=2 re-tiling (halves the per-pass frag
// stream: 2048 waves x 256 KB instead of 4096; halves per-MFMA VALU overhead)
// and (2) barrier every 4 tiles (L1 window 4 blk x 8 KB -> frag reads become
// L1 hits instead of thrashing to L2 -- r7/r8 both pinned at ~124 us by this).
// Rescore/epilogue/margin logic bit-identical to the r5/r7/r8 PASSES.
// out: [N*D] quantized_st | [1] loss | [N] idx (as float)
// ws: [8192] f32 en2[K] | [16384] f32 en[K*64] | [540672] u32 frags[K*32]

#define D 64
#define EPS 1e-12f
#define WPB 2              // waves per block (vq_main)
#define RG 4               // row-groups (16 rows) per wave
#define RPW (RG * 16)      // 64 rows per wave
#define RPB (WPB * RPW)    // 128 rows per block
#define CAP 832            // u32 candidate entries per wave
#define MARGIN 0.010f      // > 2*delta; delta = bf16 dot err (<=3.9e-3) + 1e-6

typedef short bf16x8 __attribute__((ext_vector_type(8)));
typedef float f32x4 __attribute__((ext_vector_type(4)));

__device__ __forceinline__ uint32_t f2bf(float f) {   // RNE f32->bf16 (finite)
    uint32_t u = __builtin_bit_cast(uint32_t, f);
    return (u + 0x7FFFu + ((u >> 16) & 1u)) >> 16;
}
// xn LDS swizzle: float4-slot XOR by row&7 -> conflict-free frag/row access
__device__ __forceinline__ int xsw(int row, int d) {
    return row * 64 + ((((d >> 2) ^ (row & 7)) << 2) | (d & 3));
}

// ---------- Kernel 1: normalize codebook + build bf16 A-fragments ----------
// (verified r7/r8) One block per 16-code tile; wave w normalizes code row
// tile*16+w; wave 0 packs fragments; block 0 zeroes the loss slot.
__global__ __launch_bounds__(1024) void vq_prep(const float* __restrict__ emb,
                                                float* __restrict__ en,
                                                float* __restrict__ en2,
                                                uint32_t* __restrict__ frags,
                                                float* __restrict__ loss_out,
                                                int K) {
    __shared__ float sh[16][64];
    int w = (int)(threadIdx.x >> 6), lane = (int)(threadIdx.x & 63);
    int tile = (int)blockIdx.x;
    int row = tile * 16 + w;
    if (row < K) {
        float v = emb[(size_t)row * D + lane];
        float s = v * v;
        #pragma unroll
        for (int m = 32; m >= 1; m >>= 1) s += __shfl_xor(s, m, 64);
        float e = v / fmaxf(sqrtf(s), EPS);      // division: F.normalize fidelity
        float s2 = e * e;
        #pragma unroll
        for (int m = 32; m >= 1; m >>= 1) s2 += __shfl_xor(s2, m, 64);
        en[(size_t)row * D + lane] = e;
        if (lane == 0) en2[row] = s2;
        sh[w][lane] = e;
    }
    if (blockIdx.x == 0 && threadIdx.x == 0) loss_out[0] = 0.f;
    __syncthreads();
    if (w == 0) {                                // wave 0 packs the tile
        int cl = lane & 15, dbase = (lane >> 4) * 8;
        #pragma unroll
        for (int h = 0; h < 2; ++h) {
            const float* p = &sh[cl][h * 32 + dbase];
            uint4 u;
            u.x = f2bf(p[0]) | (f2bf(p[1]) << 16);
            u.y = f2bf(p[2]) | (f2bf(p[3]) << 16);
            u.z = f2bf(p[4]) | (f2bf(p[5]) << 16);
            u.w = f2bf(p[6]) | (f2bf(p[7]) << 16);
            *(uint4*)(frags + ((size_t)(tile * 2 + h) * 64 + lane) * 4) = u;
        }
    }
}

// ---------------- Kernel 2: main ----------------
__global__ __launch_bounds__(128, 2) void vq_main(const float* __restrict__ x,
                                                  const float* __restrict__ en,
                                                  const float* __restrict__ en2g,
                                                  const uint32_t* __restrict__ frags,
                                                  float* __restrict__ out_q,
                                                  float* __restrict__ out_idx,
                                                  float* __restrict__ loss_out,
                                                  int N, int K) {
    __shared__ float xn[RPB * 64];             // 32 KB, swizzled via xsw()
    __shared__ uint32_t cand[WPB][CAP];        // 6.5 KB, (k<<6)|rloc
    __shared__ int candcnt[WPB];
    __shared__ unsigned long long keys[RPB];   // 1 KB
    __shared__ double red[WPB];
    // total ~39.6 KB -> 4 blocks/CU (8 waves/CU, 2/SIMD)

    const int tid = (int)threadIdx.x;
    const int w = tid >> 6, lane = tid & 63;
    const int rowbase = (int)blockIdx.x * RPB;
    const int NT = K / 16;                     // 128 tiles
    const int lq = (lane >> 4) << 2;           // k-quad base within tile

    // ---- phase 0 (arithmetic bit-identical to r5-r8; 4 rows in flight) ----
    for (int r0 = 0; r0 < RPW; r0 += 4) {
        float v[4];
        #pragma unroll
        for (int j = 0; j < 4; ++j)
            v[j] = x[(size_t)(rowbase + w * RPW + r0 + j) * D + lane];
        #pragma unroll
        for (int j = 0; j < 4; ++j) {
            float s = v[j] * v[j];
            #pragma unroll
            for (int m = 32; m >= 1; m >>= 1) s += __shfl_xor(s, m, 64);
            xn[xsw(w * RPW + r0 + j, lane)] = v[j] / fmaxf(sqrtf(s), EPS);
        }
    }
    if (lane == 0) candcnt[w] = 0;
    keys[tid] = ~0ull;                         // blockDim == RPB

    // ---- B-fragments in registers (mapping verified r3-r8) ----
    bf16x8 bfr[RG][2];
    #pragma unroll
    for (int g = 0; g < RG; ++g)
        #pragma unroll
        for (int h = 0; h < 2; ++h) {
            int row = w * RPW + g * 16 + (lane & 15);
            int db = h * 32 + ((lane >> 4) * 8);
            union { uint32_t u[4]; bf16x8 v; } cvt;
            #pragma unroll
            for (int j = 0; j < 4; ++j)
                cvt.u[j] = f2bf(xn[xsw(row, db + 2 * j)]) |
                           (f2bf(xn[xsw(row, db + 2 * j + 1)]) << 16);
            bfr[g][h] = cvt.v;
        }

    const f32x4 zero4 = {0.f, 0.f, 0.f, 0.f};
    const bf16x8* fb = (const bf16x8*)frags + lane;  // 16 B/lane, tile stride 128

    // ======== PASS 1: lean max scan (no shfl, no atomics, no branches) ======
    f32x4 rmax[RG];
    #pragma unroll
    for (int g = 0; g < RG; ++g) rmax[g] = {-3.0e38f, -3.0e38f, -3.0e38f, -3.0e38f};
    {
        const bf16x8* p = fb;
        bf16x8 A0 = p[0], A1 = p[64];
        for (int t = 0; t < NT; t += 2) {
            bf16x8 B0 = p[128], B1 = p[192];             // prefetch tile t+1
            #pragma unroll
            for (int g = 0; g < RG; ++g) {
                f32x4 acc = __builtin_amdgcn_mfma_f32_16x16x32_bf16(A0, bfr[g][0], zero4, 0, 0, 0);
                acc = __builtin_amdgcn_mfma_f32_16x16x32_bf16(A1, bfr[g][1], acc, 0, 0, 0);
                #pragma unroll
                for (int q = 0; q < 4; ++q) rmax[g][q] = fmaxf(rmax[g][q], acc[q]);
            }
            if (t + 2 < NT) { A0 = p[256]; A1 = p[320]; } // prefetch tile t+2
            #pragma unroll
            for (int g = 0; g < RG; ++g) {
                f32x4 acc = __builtin_amdgcn_mfma_f32_16x16x32_bf16(B0, bfr[g][0], zero4, 0, 0, 0);
                acc = __builtin_amdgcn_mfma_f32_16x16x32_bf16(B1, bfr[g][1], acc, 0, 0, 0);
                #pragma unroll
                for (int q = 0; q < 4; ++q) rmax[g][q] = fmaxf(rmax[g][q], acc[q]);
            }
            p += 256;
            if ((t & 3) == 2) __syncthreads();   // tight lockstep: L1 window 8KB/blk
        }
    }
    float tau[RG];
    #pragma unroll
    for (int g = 0; g < RG; ++g) {
        float m = fmaxf(fmaxf(rmax[g][0], rmax[g][1]), fmaxf(rmax[g][2], rmax[g][3]));
        m = fmaxf(m, __shfl_xor(m, 16, 64));
        m = fmaxf(m, __shfl_xor(m, 32, 64));
        tau[g] = m - MARGIN;
    }

    // ======== PASS 2: recompute (bit-identical MFMA) + collect vs tau =======
    {
        const bf16x8* p = fb;
        bf16x8 A0 = p[0], A1 = p[64];
        for (int t = 0; t < NT; ++t) {
            bf16x8 nA0, nA1;
            if (t + 1 < NT) { nA0 = p[128]; nA1 = p[192]; }
            int cb = t * 16 + lq;
            #pragma unroll
            for (int g = 0; g < RG; ++g) {
                f32x4 acc = __builtin_amdgcn_mfma_f32_16x16x32_bf16(A0, bfr[g][0], zero4, 0, 0, 0);
                acc = __builtin_amdgcn_mfma_f32_16x16x32_bf16(A1, bfr[g][1], acc, 0, 0, 0);
                float m4 = fmaxf(fmaxf(acc[0], acc[1]), fmaxf(acc[2], acc[3]));
                if (__any(m4 >= tau[g])) {                // ~17% of tiles
                    int rloc = g * 16 + (lane & 15);
                    #pragma unroll
                    for (int q = 0; q < 4; ++q) {
                        if (acc[q] >= tau[g]) {
                            int k = cb + q;
                            int slot = atomicAdd(&candcnt[w], 1);
                            if (slot < CAP) {
                                cand[w][slot] = ((uint32_t)k << 6) | (uint32_t)rloc;
                            } else {   // overflow fallback: inline exact rescore
                                const float* ev = en + (size_t)k * D;
                                float dot = 0.f;
                                #pragma unroll
                                for (int d0 = 0; d0 < D; ++d0)
                                    dot = fmaf(xn[xsw(w * RPW + rloc, d0)], ev[d0], dot);
                                float R = fmaf(-0.5f, en2g[k], dot);
                                uint32_t fbt = __builtin_bit_cast(uint32_t, -R);
                                uint32_t ord = (fbt & 0x80000000u) ? ~fbt : (fbt | 0x80000000u);
                                atomicMin(&keys[w * RPW + rloc],
                                          ((unsigned long long)ord << 32) | (uint32_t)k);
                            }
                        }
                    }
                }
            }
            A0 = nA0; A1 = nA1;
            p += 128;
            if ((t & 3) == 3) __syncthreads();           // tight lockstep
        }
    }

    // ---- exact fp32 rescore (arithmetic bit-identical to r3-r8) ----
    int cnt = candcnt[w];
    cnt = cnt < CAP ? cnt : CAP;
    for (int base = 0; base < cnt; base += 64) {
        int i = base + lane;
        if (i < cnt) {
            uint32_t e = cand[w][i];
            int k = (int)(e >> 6), rloc = (int)(e & 63u);
            const float* ev = en + (size_t)k * D;
            float dot = 0.f;
            #pragma unroll
            for (int d0 = 0; d0 < D; ++d0)
                dot = fmaf(xn[xsw(w * RPW + rloc, d0)], ev[d0], dot);
            float R = fmaf(-0.5f, en2g[k], dot);
            uint32_t fbt = __builtin_bit_cast(uint32_t, -R);  // minimize -R
            uint32_t ord = (fbt & 0x80000000u) ? ~fbt : (fbt | 0x80000000u);
            atomicMin(&keys[w * RPW + rloc],                  // ties -> smaller k
                      ((unsigned long long)ord << 32) | (uint32_t)k);
        }
    }

    // ---- epilogue (wave-local rows; 4 gathers in flight) ----
    float ls = 0.f;
    for (int r0 = 0; r0 < RPW; r0 += 4) {
        int kk[4];
        float qv[4];
        #pragma unroll
        for (int j = 0; j < 4; ++j)
            kk[j] = (int)(keys[w * RPW + r0 + j] & 0x7FFull);
        #pragma unroll
        for (int j = 0; j < 4; ++j)
            qv[j] = en[(size_t)kk[j] * D + lane];
        #pragma unroll
        for (int j = 0; j < 4; ++j) {
            float rn = fmaxf(sqrtf(en2g[kk[j]]), EPS);
            float q = qv[j] / rn;                  // l2norm(en[k]) exactly
            float a = xn[xsw(w * RPW + r0 + j, lane)];
            float dx = q - a;
            ls = fmaf(dx, dx, ls);
            out_q[(size_t)(rowbase + w * RPW + r0 + j) * D + lane] = a + dx;
        }
    }
    out_idx[rowbase + w * RPW + lane] =
        (float)(int)(keys[w * RPW + lane] & 0x7FFull);   // RPW == 64 lanes
    #pragma unroll
    for (int m = 32; m >= 1; m >>= 1) ls += __shfl_xor(ls, m, 64);
    if (lane == 0) red[w] = (double)ls;
    __syncthreads();
    if (tid == 0) {
        double s = red[0] + red[1];
        // loss = 1.25 * sum/(N*D); fp32 atomic accumulation (verified r7/r8)
        atomicAdd(loss_out, (float)(s * (1.25 / ((double)N * (double)D))));
    }
}

extern "C" void kernel_launch(void* const* d_in, const int* in_sizes, int n_in,
                              void* d_out, int out_size, void* d_ws, size_t ws_size,
                              hipStream_t stream) {
    const float* x   = (const float*)d_in[0];
    const float* emb = (const float*)d_in[1];
    int N = in_sizes[0] / D;
    int K = in_sizes[1] / D;

    float* out      = (float*)d_out;
    float* out_q    = out;
    float* loss_out = out + (size_t)N * D;
    float* out_idx  = out + (size_t)N * D + 1;

    char* ws = (char*)d_ws;
    float*    en2   = (float*)(ws + 8192);               // 8 KB
    float*    en    = (float*)(ws + 16384);              // 512 KB
    uint32_t* frags = (uint32_t*)(ws + 540672);          // 256 KB

    vq_prep<<<K / 16, 1024, 0, stream>>>(emb, en, en2, frags, loss_out, K);
    vq_main<<<N / RPB, 128, 0, stream>>>(x, en, en2, frags, out_q, out_idx,
                                         loss_out, N, K);
}

// Round 10
// 179.737 us; speedup vs baseline: 1.1168x; 1.1168x over previous
//
#include <hip/hip_runtime.h>
#include <math.h>
#include <stdint.h>

// VectorQuantizer on MI355X (gfx950). N=131072, D=64, K=2048, fp32.
// Round 10: r8 tiling (RG=2, WPB=4, 16 waves/CU) + (1) ZERO barriers in the
// scan/rescore path (scan state is wave-local; r8's lockstep barrier forced a
// vmcnt(0) drain every 16 tiles, exposing full L2 latency to all waves), and
// (2) 4-deep static prefetch ring (use-to-issue distance ~4 rounds covers
// contended L2 latency; r8's 1-deep was ~60 cyc). r9 (fewer waves, less
// traffic) got WORSE -> latency-bound, not BW-bound; this attacks latency.
// Rescore/epilogue/margin logic bit-identical to the r5/r7/r8 PASSES.
// out: [N*D] quantized_st | [1] loss | [N] idx (as float)
// ws: [8192] f32 en2[K] | [16384] f32 en[K*64] | [540672] u32 frags[K*32]

#define D 64
#define EPS 1e-12f
#define WPB 4              // waves per block (vq_main)
#define RG 2               // row-groups (16 rows) per wave
#define RPW (RG * 16)      // 32 rows per wave
#define RPB (WPB * RPW)    // 128 rows per block
#define CAP 832            // u16 candidate entries per wave
#define MARGIN 0.010f      // > 2*delta; delta = bf16 dot err (<=3.9e-3) + 1e-6

typedef short bf16x8 __attribute__((ext_vector_type(8)));
typedef float f32x4 __attribute__((ext_vector_type(4)));

__device__ __forceinline__ uint32_t f2bf(float f) {   // RNE f32->bf16 (finite)
    uint32_t u = __builtin_bit_cast(uint32_t, f);
    return (u + 0x7FFFu + ((u >> 16) & 1u)) >> 16;
}
// xn LDS swizzle: float4-slot XOR by row&7 -> conflict-free frag/row access
__device__ __forceinline__ int xsw(int row, int d) {
    return row * 64 + ((((d >> 2) ^ (row & 7)) << 2) | (d & 3));
}

// ---------- Kernel 1: normalize codebook + build bf16 A-fragments ----------
// (verified r7/r8/r9) One block per 16-code tile; wave w normalizes code row
// tile*16+w; wave 0 packs fragments; block 0 zeroes the loss slot.
__global__ __launch_bounds__(1024) void vq_prep(const float* __restrict__ emb,
                                                float* __restrict__ en,
                                                float* __restrict__ en2,
                                                uint32_t* __restrict__ frags,
                                                float* __restrict__ loss_out,
                                                int K) {
    __shared__ float sh[16][64];
    int w = (int)(threadIdx.x >> 6), lane = (int)(threadIdx.x & 63);
    int tile = (int)blockIdx.x;
    int row = tile * 16 + w;
    if (row < K) {
        float v = emb[(size_t)row * D + lane];
        float s = v * v;
        #pragma unroll
        for (int m = 32; m >= 1; m >>= 1) s += __shfl_xor(s, m, 64);
        float e = v / fmaxf(sqrtf(s), EPS);      // division: F.normalize fidelity
        float s2 = e * e;
        #pragma unroll
        for (int m = 32; m >= 1; m >>= 1) s2 += __shfl_xor(s2, m, 64);
        en[(size_t)row * D + lane] = e;
        if (lane == 0) en2[row] = s2;
        sh[w][lane] = e;
    }
    if (blockIdx.x == 0 && threadIdx.x == 0) loss_out[0] = 0.f;
    __syncthreads();
    if (w == 0) {                                // wave 0 packs the tile
        int cl = lane & 15, dbase = (lane >> 4) * 8;
        #pragma unroll
        for (int h = 0; h < 2; ++h) {
            const float* p = &sh[cl][h * 32 + dbase];
            uint4 u;
            u.x = f2bf(p[0]) | (f2bf(p[1]) << 16);
            u.y = f2bf(p[2]) | (f2bf(p[3]) << 16);
            u.z = f2bf(p[4]) | (f2bf(p[5]) << 16);
            u.w = f2bf(p[6]) | (f2bf(p[7]) << 16);
            *(uint4*)(frags + ((size_t)(tile * 2 + h) * 64 + lane) * 4) = u;
        }
    }
}

// ---------------- Kernel 2: main ----------------
__global__ __launch_bounds__(256, 4) void vq_main(const float* __restrict__ x,
                                                  const float* __restrict__ en,
                                                  const float* __restrict__ en2g,
                                                  const uint32_t* __restrict__ frags,
                                                  float* __restrict__ out_q,
                                                  float* __restrict__ out_idx,
                                                  float* __restrict__ loss_out,
                                                  int N, int K) {
    __shared__ float xn[RPB * 64];             // 32 KB, swizzled via xsw()
    __shared__ uint16_t cand[WPB][CAP];        // 6.5 KB, (k<<5)|rloc
    __shared__ int candcnt[WPB];
    __shared__ unsigned long long keys[RPB];   // 1 KB
    __shared__ double red[WPB];
    // total ~39.7 KB -> 4 blocks/CU (16 waves/CU, 4/SIMD)

    const int tid = (int)threadIdx.x;
    const int w = tid >> 6, lane = tid & 63;
    const int rowbase = (int)blockIdx.x * RPB;
    const int NT = K / 16;                     // 128 tiles
    const int lq = (lane >> 4) << 2;           // k-quad base within tile

    // ---- phase 0 (arithmetic bit-identical to r5-r9; wave-local) ----
    for (int r = 0; r < RPW; ++r) {
        int rb = w * RPW + r;
        float v = x[(size_t)(rowbase + rb) * D + lane];
        float s = v * v;
        #pragma unroll
        for (int m = 32; m >= 1; m >>= 1) s += __shfl_xor(s, m, 64);
        xn[xsw(rb, lane)] = v / fmaxf(sqrtf(s), EPS);
    }
    if (lane == 0) candcnt[w] = 0;
    if (lane < RPW) keys[w * RPW + lane] = ~0ull;

    // ---- B-fragments in registers (mapping verified r3-r9) ----
    bf16x8 bfr[RG][2];
    #pragma unroll
    for (int g = 0; g < RG; ++g)
        #pragma unroll
        for (int h = 0; h < 2; ++h) {
            int row = w * RPW + g * 16 + (lane & 15);
            int db = h * 32 + ((lane >> 4) * 8);
            union { uint32_t u[4]; bf16x8 v; } cvt;
            #pragma unroll
            for (int j = 0; j < 4; ++j)
                cvt.u[j] = f2bf(xn[xsw(row, db + 2 * j)]) |
                           (f2bf(xn[xsw(row, db + 2 * j + 1)]) << 16);
            bfr[g][h] = cvt.v;
        }

    const f32x4 zero4 = {0.f, 0.f, 0.f, 0.f};
    const bf16x8* fb = (const bf16x8*)frags + lane;  // 16 B/lane; tile t frag h at [t*128+h*64]

    // ======== PASS 1: lean max scan, 4-deep prefetch ring, NO barriers ======
    f32x4 rmax[RG];
    #pragma unroll
    for (int g = 0; g < RG; ++g) rmax[g] = {-3.0e38f, -3.0e38f, -3.0e38f, -3.0e38f};
    {
        bf16x8 A[4][2];
        #pragma unroll
        for (int i = 0; i < 4; ++i) {
            A[i][0] = fb[i * 128];
            A[i][1] = fb[i * 128 + 64];
        }
        for (int t = 0; t < NT; t += 4) {
            #pragma unroll
            for (int i = 0; i < 4; ++i) {
                #pragma unroll
                for (int g = 0; g < RG; ++g) {
                    f32x4 acc = __builtin_amdgcn_mfma_f32_16x16x32_bf16(A[i][0], bfr[g][0], zero4, 0, 0, 0);
                    acc = __builtin_amdgcn_mfma_f32_16x16x32_bf16(A[i][1], bfr[g][1], acc, 0, 0, 0);
                    #pragma unroll
                    for (int q = 0; q < 4; ++q) rmax[g][q] = fmaxf(rmax[g][q], acc[q]);
                }
                int tn = t + 4 + i; tn = (tn < NT) ? tn : 0;  // uniform clamp (tail)
                A[i][0] = fb[tn * 128];
                A[i][1] = fb[tn * 128 + 64];
            }
        }
    }
    float tau[RG];
    #pragma unroll
    for (int g = 0; g < RG; ++g) {
        float m = fmaxf(fmaxf(rmax[g][0], rmax[g][1]), fmaxf(rmax[g][2], rmax[g][3]));
        m = fmaxf(m, __shfl_xor(m, 16, 64));
        m = fmaxf(m, __shfl_xor(m, 32, 64));
        tau[g] = m - MARGIN;
    }

    // ======== PASS 2: recompute (bit-identical MFMA) + collect vs tau ======
    {
        bf16x8 A[4][2];
        #pragma unroll
        for (int i = 0; i < 4; ++i) {
            A[i][0] = fb[i * 128];
            A[i][1] = fb[i * 128 + 64];
        }
        for (int t = 0; t < NT; t += 4) {
            #pragma unroll
            for (int i = 0; i < 4; ++i) {
                int cb = (t + i) * 16 + lq;
                #pragma unroll
                for (int g = 0; g < RG; ++g) {
                    f32x4 acc = __builtin_amdgcn_mfma_f32_16x16x32_bf16(A[i][0], bfr[g][0], zero4, 0, 0, 0);
                    acc = __builtin_amdgcn_mfma_f32_16x16x32_bf16(A[i][1], bfr[g][1], acc, 0, 0, 0);
                    float m4 = fmaxf(fmaxf(acc[0], acc[1]), fmaxf(acc[2], acc[3]));
                    if (__any(m4 >= tau[g])) {            // ~17% of tiles
                        int rloc = g * 16 + (lane & 15);
                        #pragma unroll
                        for (int q = 0; q < 4; ++q) {
                            if (acc[q] >= tau[g]) {
                                int k = cb + q;
                                int slot = atomicAdd(&candcnt[w], 1);
                                if (slot < CAP) {
                                    cand[w][slot] = (uint16_t)((k << 5) | rloc);
                                } else {   // overflow fallback: inline exact rescore
                                    const float* ev = en + (size_t)k * D;
                                    float dot = 0.f;
                                    #pragma unroll
                                    for (int d0 = 0; d0 < D; ++d0)
                                        dot = fmaf(xn[xsw(w * RPW + rloc, d0)], ev[d0], dot);
                                    float R = fmaf(-0.5f, en2g[k], dot);
                                    uint32_t fbt = __builtin_bit_cast(uint32_t, -R);
                                    uint32_t ord = (fbt & 0x80000000u) ? ~fbt : (fbt | 0x80000000u);
                                    atomicMin(&keys[w * RPW + rloc],
                                              ((unsigned long long)ord << 32) | (uint32_t)k);
                                }
                            }
                        }
                    }
                }
                int tn = t + 4 + i; tn = (tn < NT) ? tn : 0;  // uniform clamp (tail)
                A[i][0] = fb[tn * 128];
                A[i][1] = fb[tn * 128 + 64];
            }
        }
    }

    // ---- exact fp32 rescore (arithmetic bit-identical to r3-r9) ----
    int cnt = candcnt[w];
    cnt = cnt < CAP ? cnt : CAP;
    for (int base = 0; base < cnt; base += 64) {
        int i = base + lane;
        if (i < cnt) {
            uint32_t e = cand[w][i];
            int k = (int)(e >> 5), rloc = (int)(e & 31u);
            const float* ev = en + (size_t)k * D;
            float dot = 0.f;
            #pragma unroll
            for (int d0 = 0; d0 < D; ++d0)
                dot = fmaf(xn[xsw(w * RPW + rloc, d0)], ev[d0], dot);
            float R = fmaf(-0.5f, en2g[k], dot);
            uint32_t fbt = __builtin_bit_cast(uint32_t, -R);  // minimize -R
            uint32_t ord = (fbt & 0x80000000u) ? ~fbt : (fbt | 0x80000000u);
            atomicMin(&keys[w * RPW + rloc],                  // ties -> smaller k
                      ((unsigned long long)ord << 32) | (uint32_t)k);
        }
    }

    // ---- epilogue (wave-local rows; bit-identical to r5/r7/r8) ----
    float ls = 0.f;
    for (int r = 0; r < RPW; ++r) {
        int rb = w * RPW + r;
        int k = (int)(keys[rb] & 0x7FFull);
        float rn = fmaxf(sqrtf(en2g[k]), EPS);
        float q = en[(size_t)k * D + lane] / rn;       // l2norm(en[k]) exactly
        float a = xn[xsw(rb, lane)];
        float dx = q - a;
        ls = fmaf(dx, dx, ls);
        out_q[(size_t)(rowbase + rb) * D + lane] = a + dx;   // xn + (q - xn)
    }
    if (lane < RPW) out_idx[rowbase + w * RPW + lane] =
        (float)(int)(keys[w * RPW + lane] & 0x7FFull);
    #pragma unroll
    for (int m = 32; m >= 1; m >>= 1) ls += __shfl_xor(ls, m, 64);
    if (lane == 0) red[w] = (double)ls;
    __syncthreads();                               // ONLY barrier in the kernel
    if (tid == 0) {
        double s = 0.0;
        #pragma unroll
        for (int i = 0; i < WPB; ++i) s += red[i];
        // loss = 1.25 * sum/(N*D); fp32 atomic accumulation (verified r7/r8)
        atomicAdd(loss_out, (float)(s * (1.25 / ((double)N * (double)D))));
    }
}

extern "C" void kernel_launch(void* const* d_in, const int* in_sizes, int n_in,
                              void* d_out, int out_size, void* d_ws, size_t ws_size,
                              hipStream_t stream) {
    const float* x   = (const float*)d_in[0];
    const float* emb = (const float*)d_in[1];
    int N = in_sizes[0] / D;
    int K = in_sizes[1] / D;

    float* out      = (float*)d_out;
    float* out_q    = out;
    float* loss_out = out + (size_t)N * D;
    float* out_idx  = out + (size_t)N * D + 1;

    char* ws = (char*)d_ws;
    float*    en2   = (float*)(ws + 8192);               // 8 KB
    float*    en    = (float*)(ws + 16384);              // 512 KB
    uint32_t* frags = (uint32_t*)(ws + 540672);          // 256 KB

    vq_prep<<<K / 16, 1024, 0, stream>>>(emb, en, en2, frags, loss_out, K);
    vq_main<<<N / RPB, 256, 0, stream>>>(x, en, en2, frags, out_q, out_idx,
                                         loss_out, N, K);
}